// Round 12
// baseline (455.102 us; speedup 1.0000x reference)
//
#include <hip/hip_runtime.h>
#include <hip/hip_fp16.h>
#include <cstdint>

typedef int v4i __attribute__((ext_vector_type(4)));

#define AS1C(p) ((const __attribute__((address_space(1))) void*)(p))
#define AS3(p)  ((__attribute__((address_space(3))) void*)(p))

// ---------------------------------------------------------------------------
// Fused per-row symmetric int8 quantization (single pass, row in registers).
// ---------------------------------------------------------------------------
__global__ __launch_bounds__(256) void quant_fused(const float* __restrict__ X,
                                                   const float* __restrict__ W,
                                                   int8_t* __restrict__ Xq,
                                                   int8_t* __restrict__ Wq,
                                                   float* __restrict__ a_scale,
                                                   float* __restrict__ w_scale) {
    const int row = blockIdx.x;
    const bool isW = row >= 8192;
    const int r = isW ? row - 8192 : row;
    const float* src = (isW ? W : X) + (size_t)r * 4096;
    int8_t* dst = isW ? (Wq + (size_t)r * 4096) : (Xq + (size_t)r * 4096);
    float* scp = (isW ? w_scale : a_scale) + r;

    const float4* xv = (const float4*)src;
    const int tid = threadIdx.x;

    float4 v[4];
#pragma unroll
    for (int j = 0; j < 4; ++j) v[j] = xv[tid + (j << 8)];

    float m = 0.0f;
#pragma unroll
    for (int j = 0; j < 4; ++j) {
        m = fmaxf(m, fmaxf(fmaxf(fabsf(v[j].x), fabsf(v[j].y)),
                           fmaxf(fabsf(v[j].z), fabsf(v[j].w))));
    }
    for (int off = 32; off > 0; off >>= 1)
        m = fmaxf(m, __shfl_xor(m, off, 64));

    __shared__ float wmax[4];
    __shared__ float s_sc;
    const int lane = tid & 63;
    const int wv = tid >> 6;
    if (lane == 0) wmax[wv] = m;
    __syncthreads();
    if (tid == 0) {
        float mm = fmaxf(fmaxf(wmax[0], wmax[1]), fmaxf(wmax[2], wmax[3]));
        float sc = mm / 127.0f;
        *scp = sc;
        s_sc = sc;
    }
    __syncthreads();
    const float sc = s_sc;

    char4* qv = (char4*)dst;
#pragma unroll
    for (int j = 0; j < 4; ++j) {
        char4 q;
        q.x = (signed char)(int)rintf(v[j].x / sc);
        q.y = (signed char)(int)rintf(v[j].y / sc);
        q.z = (signed char)(int)rintf(v[j].z / sc);
        q.w = (signed char)(int)rintf(v[j].w / sc);
        qv[tid + (j << 8)] = q;
    }
}

// ---------------------------------------------------------------------------
// int8 GEMM, 256x256 block tile, 256 threads = 4 waves in 2x2, per-wave
// 128x128: acc[8][8] = 256 VGPRs, legal under __launch_bounds__(256,1)
// (1 wave/SIMD -> 512 VGPR budget; r10's spill came from the (256,2) cap).
// WHY: r3-r11 showed LDS-port time and MFMA time ADD in every schedule
// (measured per-tile ~= 1306 MFMA + ~1400 LDS serial; even independent
// blocks phase-lock through the shared port). 128x128 waves read 16 frags
// per 64 MFMA -> per-CU LDS demand ~1024 cyc < MFMA 1306, and only 2
// ds_reads per 163-cyc MFMA group per wave -> LDS issue-queue never fills,
// so in-order issue no longer strangles the MFMA pipe. One wave per SIMD
// saturates the matrix pipe solo.
// Schedule (r6 skeleton): 4-buffer ring (4 x 32 KiB); per tile: head
// vmcnt(8)+barrier (retires exactly tile kt+1's 8 DMA issues; kt+2/kt+3
// stay in flight ~2 tiles deep); STAGE(kt+3); 8 groups of {read next-tile
// A/B frag g into alternate reg set; 8 MFMA from current regs}@prio1.
// Ring audit: frags(kt+1) read during kt body AFTER head vmcnt(8)+barrier
// that retired kt+1's writes block-wide; STAGE(kt+3) overwrites buf
// holding kt-1 (last read during kt-2 body, barriers since). Tail clamps
// to 63: dead re-stages + one garbage next-frag read at kt=63 (unused).
// ---------------------------------------------------------------------------
__global__ __launch_bounds__(256, 1) void gemm_i8(const int8_t* __restrict__ Aq,
                                                  const int8_t* __restrict__ Bq,
                                                  const float* __restrict__ a_scale,
                                                  const float* __restrict__ w_scale,
                                                  float* __restrict__ out) {
    extern __shared__ __align__(16) int8_t smem[];  // 4 x (A 16K | B 16K)

    const int K = 4096;
    const int bid = blockIdx.x;
    const int wg  = (bid & 7) * 64 + (bid >> 3);  // bijective: 512 = 8 x 64
    const int n0 = (wg & 15) * 256;
    const int m0 = (wg >> 4) * 256;

    const int tid  = threadIdx.x;
    const int lane = tid & 63;
    const int wid  = tid >> 6;   // 0..3 (one wave per SIMD)
    const int wm   = wid >> 1;   // 0..1 -> M offset wm*128
    const int wn   = wid & 1;    // 0..1 -> N offset wn*128

    // fragment read offsets (64-B rows, 16-B-chunk XOR swizzle on row bits 1-2)
    const int rsel  = lane & 15;
    const int kswz  = ((lane >> 4) << 4) ^ (((rsel >> 1) & 3) << 4);
    const int abase = (wm * 128 + rsel) * 64 + kswz;
    const int bbase = 16384 + (wn * 128 + rsel) * 64 + kswz;

    // staging: 256 thr x 16 B = 4 KB/issue = 64 rows; pre-swizzled source col
    const int strow = tid >> 2;                       // 0..63
    const int stcol = ((tid & 3) << 4) ^ (((strow >> 1) & 3) << 4);
    const int8_t* gA = Aq + (size_t)(m0 + strow) * K + stcol;
    const int8_t* gB = Bq + (size_t)(n0 + strow) * K + stcol;
    const int ldsst = wid * 1024;  // + lane*16 by HW

    v4i acc[8][8] = {};  // 256 VGPRs
    v4i aFa[8], aFb[8], bFa[8], bFb[8];

#define STAGE(buf, kt) do {                                                          \
    int8_t* _d = smem + (buf) * 32768;                                               \
    const int8_t* _a = gA + (size_t)(kt) * 64;                                       \
    const int8_t* _b = gB + (size_t)(kt) * 64;                                       \
    _Pragma("unroll")                                                                \
    for (int i = 0; i < 4; ++i) {                                                    \
        __builtin_amdgcn_global_load_lds(AS1C(_a + (size_t)i * 64 * K),              \
                                         AS3(_d + i * 4096 + ldsst), 16, 0, 0);      \
        __builtin_amdgcn_global_load_lds(AS1C(_b + (size_t)i * 64 * K),              \
                                         AS3(_d + 16384 + i * 4096 + ldsst), 16, 0, 0); \
    }                                                                                \
  } while (0)

#define KSTEP(u, CA, CB, NA, NB, kt4) do {                                           \
    const int kt  = (kt4) + (u);                                                     \
    const int8_t* bufn = smem + (((u) + 1) & 3) * 32768;                             \
    const int ktp = (kt + 3 < 64) ? kt + 3 : 63;  /* dead re-stage at tail */        \
    asm volatile("s_waitcnt vmcnt(8)" ::: "memory");  /* retire tile kt+1 */         \
    __builtin_amdgcn_s_barrier();                                                    \
    STAGE(((u) + 3) & 3, ktp);                                                       \
    __builtin_amdgcn_sched_barrier(0);                                               \
    _Pragma("unroll")                                                                \
    for (int g = 0; g < 8; ++g) {                                                    \
        NA[g] = *(const v4i*)(bufn + abase + g * 1024);                              \
        NB[g] = *(const v4i*)(bufn + bbase + g * 1024);                              \
        __builtin_amdgcn_s_setprio(1);                                               \
        _Pragma("unroll")                                                            \
        for (int nt = 0; nt < 8; ++nt)                                               \
            acc[g][nt] = __builtin_amdgcn_mfma_i32_16x16x64_i8(                      \
                CA[g], CB[nt], acc[g][nt], 0, 0, 0);                                 \
        __builtin_amdgcn_s_setprio(0);                                               \
        __builtin_amdgcn_sched_barrier(0);                                           \
    }                                                                                \
  } while (0)

    // ---- prologue: stage tiles 0..2; retire tile 0+1; read tile-0 fragments
    STAGE(0, 0); STAGE(1, 1); STAGE(2, 2);
    asm volatile("s_waitcnt vmcnt(8)" ::: "memory");  // tiles 0 AND 1 retired
    __builtin_amdgcn_s_barrier();
#pragma unroll
    for (int g = 0; g < 8; ++g) {
        aFa[g] = *(const v4i*)(smem + abase + g * 1024);
        bFa[g] = *(const v4i*)(smem + bbase + g * 1024);
    }

    for (int kt4 = 0; kt4 < 64; kt4 += 4) {
        KSTEP(0, aFa, bFa, aFb, bFb, kt4);
        KSTEP(1, aFb, bFb, aFa, bFa, kt4);
        KSTEP(2, aFa, bFa, aFb, bFb, kt4);
        KSTEP(3, aFb, bFb, aFa, bFa, kt4);
    }

    // epilogue: C/D layout col = lane&15 (N), row = (lane>>4)*4 + reg (M)
    const int r0  = (lane >> 4) << 2;
    const int col = lane & 15;
#pragma unroll
    for (int mt = 0; mt < 8; ++mt) {
        const int tbase = m0 + wm * 128 + mt * 16 + r0;
        float as[4];
#pragma unroll
        for (int r = 0; r < 4; ++r) as[r] = a_scale[tbase + r];
#pragma unroll
        for (int nt = 0; nt < 8; ++nt) {
            const int o = n0 + wn * 128 + nt * 16 + col;
            const float wsc = w_scale[o];
#pragma unroll
            for (int r = 0; r < 4; ++r) {
                float v = (float)acc[mt][nt][r] * as[r] * wsc;
                out[(size_t)(tbase + r) * 4096 + o] = __half2float(__float2half_rn(v));
            }
        }
    }
#undef KSTEP
#undef STAGE
}

extern "C" void kernel_launch(void* const* d_in, const int* in_sizes, int n_in,
                              void* d_out, int out_size, void* d_ws, size_t ws_size,
                              hipStream_t stream) {
    const float* input_act = (const float*)d_in[0];  // [4,2048,4096] = [8192,4096]
    const float* weight    = (const float*)d_in[1];  // [4096,4096]
    float* out = (float*)d_out;

    const int K = 4096, O = 4096, T = 8192;

    int8_t* x_q = (int8_t*)d_ws;
    int8_t* w_q = x_q + (size_t)T * K;
    float* a_scale = (float*)(w_q + (size_t)O * K);
    float* w_scale = a_scale + T;

    static bool attr_done = false;
    if (!attr_done) {
        hipFuncSetAttribute(reinterpret_cast<const void*>(gemm_i8),
                            hipFuncAttributeMaxDynamicSharedMemorySize, 131072);
        attr_done = true;
    }

    quant_fused<<<T + O, 256, 0, stream>>>(input_act, weight, x_q, w_q,
                                           a_scale, w_scale);

    dim3 grid(512);  // (8192/256) x (4096/256), XCD-swizzled in-kernel
    gemm_i8<<<grid, 256, 131072, stream>>>(x_q, w_q, a_scale, w_scale, out);
}

// Round 16
// 177.051 us; speedup vs baseline: 2.5705x; 2.5705x over previous
//
#include <hip/hip_runtime.h>
#include <hip/hip_fp16.h>
#include <cstdint>

typedef int v4i __attribute__((ext_vector_type(4)));

#define AS1C(p) ((const __attribute__((address_space(1))) void*)(p))
#define AS3(p)  ((__attribute__((address_space(3))) void*)(p))

// ---------------------------------------------------------------------------
// Fused per-row symmetric int8 quantization for BOTH activations and weights:
// one launch, 12288 blocks (rows 0..8191 = activations, 8192..12287 = weight).
// Single pass — the 16 KB row lives in 16 VGPRs between absmax and quantize.
// ---------------------------------------------------------------------------
__global__ __launch_bounds__(256) void quant_fused(const float* __restrict__ X,
                                                   const float* __restrict__ W,
                                                   int8_t* __restrict__ Xq,
                                                   int8_t* __restrict__ Wq,
                                                   float* __restrict__ a_scale,
                                                   float* __restrict__ w_scale) {
    const int row = blockIdx.x;
    const float* src;
    int8_t* dst;
    float* scp;
    if (row < 8192) {
        src = X + (size_t)row * 4096;  dst = Xq + (size_t)row * 4096;  scp = a_scale + row;
    } else {
        const int r = row - 8192;
        src = W + (size_t)r * 4096;    dst = Wq + (size_t)r * 4096;    scp = w_scale + r;
    }
    const float4* xv = (const float4*)src;

    float4 v[4];
#pragma unroll
    for (int j = 0; j < 4; ++j) v[j] = xv[threadIdx.x + (j << 8)];

    float m = 0.0f;
#pragma unroll
    for (int j = 0; j < 4; ++j) {
        m = fmaxf(m, fmaxf(fmaxf(fabsf(v[j].x), fabsf(v[j].y)),
                           fmaxf(fabsf(v[j].z), fabsf(v[j].w))));
    }
    for (int off = 32; off > 0; off >>= 1)
        m = fmaxf(m, __shfl_xor(m, off, 64));

    __shared__ float wmax[4];
    __shared__ float s_sc;
    const int lane = threadIdx.x & 63;
    const int wv = threadIdx.x >> 6;
    if (lane == 0) wmax[wv] = m;
    __syncthreads();
    if (threadIdx.x == 0) {
        float mm = fmaxf(fmaxf(wmax[0], wmax[1]), fmaxf(wmax[2], wmax[3]));
        float sc = mm / 127.0f;
        *scp = sc;
        s_sc = sc;
    }
    __syncthreads();
    const float sc = s_sc;

    char4* qv = (char4*)dst;
#pragma unroll
    for (int j = 0; j < 4; ++j) {
        char4 q;
        q.x = (signed char)(int)rintf(v[j].x / sc);
        q.y = (signed char)(int)rintf(v[j].y / sc);
        q.z = (signed char)(int)rintf(v[j].z / sc);
        q.w = (signed char)(int)rintf(v[j].w / sc);
        qv[threadIdx.x + (j << 8)] = q;
    }
}

// ---------------------------------------------------------------------------
// int8 GEMM, 256x256 tile, 512 threads = 8 waves (2M x 4N), per-wave 128x64.
// 4-buffer LDS ring (128 KiB), BK=64 B, register-double-buffered fragments,
// 4 groups/tile of { 3 ds_read (next tile) + 1 global_load_lds + 8 MFMA }.
// Static role split by SIMD sibling (waves 0-3: reads->MFMA; waves 4-7:
// MFMA->reads) + setprio(1) scoped to the MFMA clusters. Best verified
// configuration of the session: 177.07 µs total, gemm 125-127 µs,
// MfmaUtil ~52%, bank conflicts 0, VGPR 120 (r7 measurement).
// Session record (r3-r14): the ~52% MfmaUtil wall is LDS-port demand
// (~1400 cyc/tile: 96 ds_read_b128 + 32 KB DMA writes) >= MFMA (~1306
// cyc); the two serialize under every schedule tried (interleave, T5
// scoping, role split, 2-blocks/CU). Breaking it needs acc > 128 regs in
// AGPRs: compiler spills via builtins (r12), miscompiles via inline asm
// (r13/r14, deterministic identical absmax) -> closed at HIP level.
// ---------------------------------------------------------------------------
__global__ __launch_bounds__(512, 2) void gemm_i8(const int8_t* __restrict__ Aq,
                                                  const int8_t* __restrict__ Bq,
                                                  const float* __restrict__ a_scale,
                                                  const float* __restrict__ w_scale,
                                                  float* __restrict__ out) {
    extern __shared__ __align__(16) int8_t smem[];  // 4 x (A 16K | B 16K)

    const int K = 4096;
    const int bid = blockIdx.x;
    const int wg  = (bid & 7) * 64 + (bid >> 3);  // bijective: 512 = 8 x 64
    const int n0 = (wg & 15) * 256;
    const int m0 = (wg >> 4) * 256;

    const int tid  = threadIdx.x;
    const int lane = tid & 63;
    const int wid  = tid >> 6;
    const int wm   = wid >> 2;
    const int wn   = wid & 3;

    // fragment read offsets (64-B rows, 16-B-chunk XOR swizzle)
    const int rsel  = lane & 15;
    const int kswz  = ((lane >> 4) << 4) ^ (((rsel >> 1) & 3) << 4);
    const int abase = (wm * 128 + rsel) * 64 + kswz;
    const int bbase = 16384 + (wn * 64 + rsel) * 64 + kswz;

    // staging: 512 thr x 16 B = 128 rows/issue; pre-swizzled global source
    const int strow = tid >> 2;
    const int stswz = ((strow >> 1) & 3) << 4;
    const int stcol = ((tid & 3) << 4) ^ stswz;
    const int8_t* gA = Aq + (size_t)(m0 + strow) * K + stcol;
    const int8_t* gB = Bq + (size_t)(n0 + strow) * K + stcol;
    const size_t rstep = (size_t)128 * K;
    const int ldsst = wid * 1024;  // + lane*16 by HW

    v4i acc[8][4] = {};
    v4i aFa[8], aFb[8], bFa[4], bFb[4];

#define STAGE(buf, kt) do {                                                          \
    int8_t* _d = smem + (buf) * 32768;                                               \
    const int8_t* _a = gA + (size_t)(kt) * 64;                                       \
    const int8_t* _b = gB + (size_t)(kt) * 64;                                       \
    __builtin_amdgcn_global_load_lds(AS1C(_a),         AS3(_d + ldsst),         16, 0, 0); \
    __builtin_amdgcn_global_load_lds(AS1C(_a + rstep), AS3(_d + 8192  + ldsst), 16, 0, 0); \
    __builtin_amdgcn_global_load_lds(AS1C(_b),         AS3(_d + 16384 + ldsst), 16, 0, 0); \
    __builtin_amdgcn_global_load_lds(AS1C(_b + rstep), AS3(_d + 24576 + ldsst), 16, 0, 0); \
  } while (0)

#define READS(g, NA, NB, gsrc, goff) do {                                            \
    NA[2*(g)]     = *(const v4i*)(bufN + abase + (2*(g))     * 1024);                \
    NA[2*(g) + 1] = *(const v4i*)(bufN + abase + (2*(g) + 1) * 1024);                \
    NB[(g)]       = *(const v4i*)(bufN + bbase + (g) * 1024);                        \
    __builtin_amdgcn_global_load_lds(AS1C(gsrc), AS3(pD + (goff) + ldsst), 16, 0, 0);\
  } while (0)

#define MFMAS(g, CA, CB) do {                                                        \
    __builtin_amdgcn_s_setprio(1);                                                   \
    _Pragma("unroll")                                                                \
    for (int nt = 0; nt < 4; ++nt) {                                                 \
        acc[2*(g)][nt] = __builtin_amdgcn_mfma_i32_16x16x64_i8(                      \
            CA[2*(g)], CB[nt], acc[2*(g)][nt], 0, 0, 0);                             \
        acc[2*(g)+1][nt] = __builtin_amdgcn_mfma_i32_16x16x64_i8(                    \
            CA[2*(g)+1], CB[nt], acc[2*(g)+1][nt], 0, 0, 0);                         \
    }                                                                                \
    __builtin_amdgcn_s_setprio(0);                                                   \
  } while (0)

    // lead role: reads feed the LDS port while the sibling's MFMAs run
#define GROUP_RW(g, CA, CB, NA, NB, gsrc, goff)  do {                                \
    READS(g, NA, NB, gsrc, goff);                                                    \
    __builtin_amdgcn_sched_barrier(0);                                               \
    MFMAS(g, CA, CB);                                                                \
    __builtin_amdgcn_sched_barrier(0);                                               \
  } while (0)

    // lag role: MFMA first (consumes last-tile registers), reads after
#define GROUP_WR(g, CA, CB, NA, NB, gsrc, goff)  do {                                \
    MFMAS(g, CA, CB);                                                                \
    __builtin_amdgcn_sched_barrier(0);                                               \
    READS(g, NA, NB, gsrc, goff);                                                    \
    __builtin_amdgcn_sched_barrier(0);                                               \
  } while (0)

#define KSTEP(G, u, CA, CB, NA, NB, kt4) do {                                        \
    const int kt  = (kt4) + (u);                                                     \
    const int8_t* bufN = smem + (((u) + 1) & 3) * 32768;                             \
    int8_t* pD = smem + (((u) + 3) & 3) * 32768;                                     \
    const int ktp = (kt + 3 < 64) ? (kt + 3) : 63;                                   \
    const int8_t* _a = gA + (size_t)ktp * 64;                                        \
    const int8_t* _b = gB + (size_t)ktp * 64;                                        \
    asm volatile("s_waitcnt vmcnt(4)" ::: "memory");                                 \
    __builtin_amdgcn_s_barrier();                                                    \
    __builtin_amdgcn_sched_barrier(0);                                               \
    G(0, CA, CB, NA, NB, _a,         0);                                             \
    G(1, CA, CB, NA, NB, _a + rstep, 8192);                                          \
    G(2, CA, CB, NA, NB, _b,         16384);                                         \
    G(3, CA, CB, NA, NB, _b + rstep, 24576);                                         \
  } while (0)

    // ---- prologue: stage tiles 0..2; retire tile 0; load its fragments
    STAGE(0, 0); STAGE(1, 1); STAGE(2, 2);
    asm volatile("s_waitcnt vmcnt(8)" ::: "memory");
    __builtin_amdgcn_s_barrier();
#pragma unroll
    for (int mt = 0; mt < 8; ++mt) aFa[mt] = *(const v4i*)(smem + abase + mt * 1024);
#pragma unroll
    for (int nt = 0; nt < 4; ++nt) bFa[nt] = *(const v4i*)(smem + bbase + nt * 1024);

    if (wid < 4) {  // lead waves: one per SIMD (wid%4 = SIMD id)
        for (int kt4 = 0; kt4 < 64; kt4 += 4) {
            KSTEP(GROUP_RW, 0, aFa, bFa, aFb, bFb, kt4);
            KSTEP(GROUP_RW, 1, aFb, bFb, aFa, bFa, kt4);
            KSTEP(GROUP_RW, 2, aFa, bFa, aFb, bFb, kt4);
            KSTEP(GROUP_RW, 3, aFb, bFb, aFa, bFa, kt4);
        }
    } else {        // lag waves: the SIMD siblings, anti-phased by construction
        for (int kt4 = 0; kt4 < 64; kt4 += 4) {
            KSTEP(GROUP_WR, 0, aFa, bFa, aFb, bFb, kt4);
            KSTEP(GROUP_WR, 1, aFb, bFb, aFa, bFa, kt4);
            KSTEP(GROUP_WR, 2, aFa, bFa, aFb, bFb, kt4);
            KSTEP(GROUP_WR, 3, aFb, bFb, aFa, bFa, kt4);
        }
    }

    // epilogue: C/D layout col = lane&15 (N), row = (lane>>4)*4 + reg (M)
    const int r0  = (lane >> 4) << 2;
    const int col = lane & 15;
#pragma unroll
    for (int mt = 0; mt < 8; ++mt) {
        const int tbase = m0 + wm * 128 + mt * 16 + r0;
        float as[4];
#pragma unroll
        for (int r = 0; r < 4; ++r) as[r] = a_scale[tbase + r];
#pragma unroll
        for (int nt = 0; nt < 4; ++nt) {
            const int o = n0 + wn * 64 + nt * 16 + col;
            const float wsc = w_scale[o];
#pragma unroll
            for (int r = 0; r < 4; ++r) {
                float v = (float)acc[mt][nt][r] * as[r] * wsc;
                out[(size_t)(tbase + r) * 4096 + o] = __half2float(__float2half_rn(v));
            }
        }
    }
#undef KSTEP
#undef GROUP_RW
#undef GROUP_WR
#undef MFMAS
#undef READS
#undef STAGE
}

extern "C" void kernel_launch(void* const* d_in, const int* in_sizes, int n_in,
                              void* d_out, int out_size, void* d_ws, size_t ws_size,
                              hipStream_t stream) {
    const float* input_act = (const float*)d_in[0];  // [4,2048,4096] = [8192,4096]
    const float* weight    = (const float*)d_in[1];  // [4096,4096]
    float* out = (float*)d_out;

    const int K = 4096, O = 4096, T = 8192;

    int8_t* x_q = (int8_t*)d_ws;
    int8_t* w_q = x_q + (size_t)T * K;
    float* a_scale = (float*)(w_q + (size_t)O * K);
    float* w_scale = a_scale + T;

    static bool attr_done = false;
    if (!attr_done) {
        hipFuncSetAttribute(reinterpret_cast<const void*>(gemm_i8),
                            hipFuncAttributeMaxDynamicSharedMemorySize, 131072);
        attr_done = true;
    }

    quant_fused<<<T + O, 256, 0, stream>>>(input_act, weight, x_q, w_q,
                                           a_scale, w_scale);

    dim3 grid(512);  // (8192/256) x (4096/256), XCD-swizzled in-kernel
    gemm_i8<<<grid, 512, 131072, stream>>>(x_q, w_q, a_scale, w_scale, out);
}